// Round 4
// baseline (78.883 us; speedup 1.0000x reference)
//
#include <hip/hip_runtime.h>
#include <math.h>

#define LSEQ 4096
#define NK 512
#define NB 16
#define SEG_G 16
#define DCHAIN 128

__global__ void build_iperm_kernel(const int* __restrict__ perm, int* __restrict__ iperm) {
    int j = threadIdx.x + blockIdx.x * blockDim.x;
    if (j < NK) iperm[perm[j]] = j;
}

template <int KS>
__device__ __forceinline__ void rocket_block(
    const float* __restrict__ xr,     // x row for batch b
    const float* __restrict__ w,      // [n, KS]
    const float* __restrict__ bias,   // [n]
    const int*   __restrict__ off,    // [n, KS]
    const int*   __restrict__ lout,   // [n]
    const int*   __restrict__ iperm,  // [NK]
    int P, int base, int li, int b,
    float* __restrict__ out)
{
    const int tid = threadIdx.x;

    float wk[KS];
#pragma unroll
    for (int k = 0; k < KS; ++k) wk[k] = w[li * KS + k];

    const int o0  = off[li * KS + 0];      // = P - pad
    const int o1  = off[li * KS + 1];      // = P - pad + d
    const int d   = o1 - o0;               // dilation (>=1)
    const int pad = P - o0;                // total pad (>=0)
    const float bi = bias[li];
    const int   Lo = lout[li];

    // interior: all taps idx = t - pad + k*d in [0, LSEQ)
    int t_lo = min(pad, Lo);
    int t_hi = min(Lo, LSEQ - (KS - 1) * d + pad);
    if (t_hi < t_lo) t_hi = t_lo;

    float mx  = -INFINITY;
    int   cnt = 0;

    // ---- left edge [0, t_lo): bounds-checked taps ----
    for (int t = tid; t < t_lo; t += 256) {
        float y = bi;
        int idx = t - pad;
#pragma unroll
        for (int k = 0; k < KS; ++k) {
            float xv = ((unsigned)idx < (unsigned)LSEQ) ? xr[idx] : 0.0f;
            y = fmaf(wk[k], xv, y);
            idx += d;
        }
        mx = fmaxf(mx, y);
        cnt += (y > 0.0f) ? 1 : 0;
    }

    // ---- interior [t_lo, t_hi) ----
    const int Ni = t_hi - t_lo;
    if (Ni > 0) {
        if (d <= DCHAIN) {
            // chain path: sliding window along t, t+d, t+2d, ...
            const unsigned ud = (unsigned)d;
            const int Mmax = (Ni + d - 1) / d;             // max outputs per chain
            const int Jmax = (Mmax + SEG_G - 1) / SEG_G;   // segments per chain
            const int nseg = d * Jmax;
            const int full_thresh = (SEG_G - 1) * d;       // rem > this => full segment
            for (int s = tid; s < nseg; s += 256) {
                const int j  = (int)((unsigned)s / ud);
                const int r  = s - j * d;
                const int t0 = t_lo + r + j * (SEG_G * d);
                if (t0 >= t_hi) continue;
                const int rem = t_hi - t0;
                const float* __restrict__ xp = xr + (t0 - pad);
                if (rem > full_thresh) {
                    // FULL segment: 16 outputs, guard-free, loads batched up-front
                    float W[KS];
                    float T[SEG_G];
#pragma unroll
                    for (int k = 0; k < KS - 1; ++k) W[k] = xp[k * d];
#pragma unroll
                    for (int g = 0; g < SEG_G; ++g) T[g] = xp[(KS - 1 + g) * d];
#pragma unroll
                    for (int g = 0; g < SEG_G; ++g) {
                        W[KS - 1] = T[g];
                        float y = bi;
#pragma unroll
                        for (int k = 0; k < KS; ++k) y = fmaf(wk[k], W[k], y);
                        mx = fmaxf(mx, y);
                        cnt += (y > 0.0f) ? 1 : 0;
#pragma unroll
                        for (int k = 0; k < KS - 1; ++k) W[k] = W[k + 1];
                    }
                } else {
                    // PARTIAL segment (<16 outputs): per-output refetch, independent loads
                    for (int t = t0; t < t_hi; t += d) {
                        const float* __restrict__ xb = xr + (t - pad);
                        float y = bi;
#pragma unroll
                        for (int k = 0; k < KS; ++k) y = fmaf(wk[k], xb[k * d], y);
                        mx = fmaxf(mx, y);
                        cnt += (y > 0.0f) ? 1 : 0;
                    }
                }
            }
        } else {
            // large-d: naive coalesced interior (taps refetched, saddr+voffset loads)
            for (int t = t_lo + tid; t < t_hi; t += 256) {
                float y = bi;
#pragma unroll
                for (int k = 0; k < KS; ++k) {
                    y = fmaf(wk[k], xr[(t - pad) + k * d], y);
                }
                mx = fmaxf(mx, y);
                cnt += (y > 0.0f) ? 1 : 0;
            }
        }
    }

    // ---- right edge [t_hi, Lo): bounds-checked taps ----
    for (int t = t_hi + tid; t < Lo; t += 256) {
        float y = bi;
        int idx = t - pad;
#pragma unroll
        for (int k = 0; k < KS; ++k) {
            float xv = ((unsigned)idx < (unsigned)LSEQ) ? xr[idx] : 0.0f;
            y = fmaf(wk[k], xv, y);
            idx += d;
        }
        mx = fmaxf(mx, y);
        cnt += (y > 0.0f) ? 1 : 0;
    }

    // ---- wave64 + block reduction ----
#pragma unroll
    for (int o = 32; o > 0; o >>= 1) {
        mx = fmaxf(mx, __shfl_down(mx, o, 64));
        cnt += __shfl_down(cnt, o, 64);
    }

    __shared__ float smx[4];
    __shared__ int   scnt[4];
    const int wid = tid >> 6;
    if ((tid & 63) == 0) { smx[wid] = mx; scnt[wid] = cnt; }
    __syncthreads();

    if (tid == 0) {
        float m = smx[0];
        int   c = scnt[0];
#pragma unroll
        for (int i = 1; i < 4; ++i) { m = fmaxf(m, smx[i]); c += scnt[i]; }
        const int j = iperm[base + li];
        out[b * (2 * NK) + 2 * j]     = m;
        out[b * (2 * NK) + 2 * j + 1] = (float)c / (float)Lo;
    }
}

__global__ __launch_bounds__(256) void rocket_fused_kernel(
    const float* __restrict__ x,
    const float* __restrict__ w0, const float* __restrict__ b0,
    const int* __restrict__ off0, const int* __restrict__ l0,
    const float* __restrict__ w1, const float* __restrict__ b1,
    const int* __restrict__ off1, const int* __restrict__ l1,
    const float* __restrict__ w2, const float* __restrict__ b2,
    const int* __restrict__ off2, const int* __restrict__ l2,
    const int* __restrict__ iperm, const int* __restrict__ Pp,
    int n0, int n01,
    float* __restrict__ out)
{
    const int gid = blockIdx.x;       // 0..511 global kernel index (group-ordered)
    const int b   = blockIdx.y;
    const int P   = *Pp;
    const float* xr = x + (size_t)b * LSEQ;

    if (gid < n0) {
        rocket_block<7>(xr, w0, b0, off0, l0, iperm, P, 0, gid, b, out);
    } else if (gid < n01) {
        rocket_block<9>(xr, w1, b1, off1, l1, iperm, P, n0, gid - n0, b, out);
    } else {
        rocket_block<11>(xr, w2, b2, off2, l2, iperm, P, n01, gid - n01, b, out);
    }
}

extern "C" void kernel_launch(void* const* d_in, const int* in_sizes, int n_in,
                              void* d_out, int out_size, void* d_ws, size_t ws_size,
                              hipStream_t stream) {
    const float* x    = (const float*)d_in[0];
    const int*   perm = (const int*)d_in[1];
    const int*   Pp   = (const int*)d_in[2];
    const float* w0   = (const float*)d_in[3];
    const float* b0   = (const float*)d_in[4];
    const int*   off0 = (const int*)d_in[5];
    const int*   l0   = (const int*)d_in[6];
    const float* w1   = (const float*)d_in[7];
    const float* b1   = (const float*)d_in[8];
    const int*   off1 = (const int*)d_in[9];
    const int*   l1   = (const int*)d_in[10];
    const float* w2   = (const float*)d_in[11];
    const float* b2   = (const float*)d_in[12];
    const int*   off2 = (const int*)d_in[13];
    const int*   l2   = (const int*)d_in[14];

    const int n0 = in_sizes[4];
    const int n1 = in_sizes[8];

    float* out = (float*)d_out;
    int* iperm = (int*)d_ws;

    build_iperm_kernel<<<1, NK, 0, stream>>>(perm, iperm);

    rocket_fused_kernel<<<dim3(NK, NB), 256, 0, stream>>>(
        x, w0, b0, off0, l0, w1, b1, off1, l1, w2, b2, off2, l2,
        iperm, Pp, n0, n0 + n1, out);
}

// Round 5
// 54.123 us; speedup vs baseline: 1.4575x; 1.4575x over previous
//
#include <hip/hip_runtime.h>
#include <math.h>

#define LSEQ 4096
#define NK 512
#define NB 16
#define ROWS 12544   // padded row stride (floats): 49*256, > 4096+2*4095+4
#define G 4

__global__ void build_iperm_kernel(const int* __restrict__ perm, int* __restrict__ iperm) {
    int j = threadIdx.x + blockIdx.x * blockDim.x;
    if (j < NK) iperm[perm[j]] = j;
}

// zero + copy: xp[b][j] = (P <= j < P+L) ? x[b][j-P] : 0
__global__ __launch_bounds__(256) void pad_x_kernel(
    const float* __restrict__ x, float* __restrict__ xp, const int* __restrict__ Pp)
{
    const int P = *Pp;
    const int j = threadIdx.x + blockIdx.x * 256;
    const int b = blockIdx.y;
    const int s = j - P;
    float v = ((unsigned)s < (unsigned)LSEQ) ? x[b * LSEQ + s] : 0.0f;
    xp[b * ROWS + j] = v;
}

// ---------------- padded fast path ----------------
template <int KS>
__device__ __forceinline__ void rocket_block_pad(
    const float* __restrict__ xp,     // padded row for batch b
    const float* __restrict__ w, const float* __restrict__ bias,
    const int* __restrict__ off, const int* __restrict__ lout,
    const int* __restrict__ iperm, int base, int li, int b,
    float* __restrict__ out)
{
    const int tid = threadIdx.x;

    float wk[KS];
    const float* pk[KS];
    int rk[KS];
#pragma unroll
    for (int k = 0; k < KS; ++k) {
        wk[k] = w[li * KS + k];
        const int o = off[li * KS + k];   // >= 0 always (P >= pad)
        pk[k] = xp + o;
        rk[k] = o & 3;                     // block-uniform alignment class
    }
    const float bi = bias[li];
    const int   Lo = lout[li];

    float mx  = -INFINITY;
    int   cnt = 0;

    for (int t = G * tid; t < Lo; t += G * 256) {
        float X[KS][G];
        // ---- load phase: alignment-specialized, all loads independent ----
#pragma unroll
        for (int k = 0; k < KS; ++k) {
            const float* a = pk[k] + t;    // t % 4 == 0, row base 16B-aligned
            if (rk[k] == 0) {
                const float4 v = *(const float4*)a;
                X[k][0] = v.x; X[k][1] = v.y; X[k][2] = v.z; X[k][3] = v.w;
            } else if (rk[k] == 2) {
                const float2 v0 = *(const float2*)a;
                const float2 v1 = *(const float2*)(a + 2);
                X[k][0] = v0.x; X[k][1] = v0.y; X[k][2] = v1.x; X[k][3] = v1.y;
            } else {
                const float2 v = *(const float2*)(a + 1);
                X[k][0] = a[0]; X[k][1] = v.x; X[k][2] = v.y; X[k][3] = a[3];
            }
        }
        // ---- compute phase ----
        float y0 = bi, y1 = bi, y2 = bi, y3 = bi;
#pragma unroll
        for (int k = 0; k < KS; ++k) {
            y0 = fmaf(wk[k], X[k][0], y0);
            y1 = fmaf(wk[k], X[k][1], y1);
            y2 = fmaf(wk[k], X[k][2], y2);
            y3 = fmaf(wk[k], X[k][3], y3);
        }
        mx = fmaxf(mx, y0); cnt += (y0 > 0.0f);
        if (t + 1 < Lo) { mx = fmaxf(mx, y1); cnt += (y1 > 0.0f); }
        if (t + 2 < Lo) { mx = fmaxf(mx, y2); cnt += (y2 > 0.0f); }
        if (t + 3 < Lo) { mx = fmaxf(mx, y3); cnt += (y3 > 0.0f); }
    }

#pragma unroll
    for (int o = 32; o > 0; o >>= 1) {
        mx = fmaxf(mx, __shfl_down(mx, o, 64));
        cnt += __shfl_down(cnt, o, 64);
    }
    __shared__ float smx[4];
    __shared__ int   scnt[4];
    const int wid = tid >> 6;
    if ((tid & 63) == 0) { smx[wid] = mx; scnt[wid] = cnt; }
    __syncthreads();
    if (tid == 0) {
        float m = smx[0]; int c = scnt[0];
#pragma unroll
        for (int i = 1; i < 4; ++i) { m = fmaxf(m, smx[i]); c += scnt[i]; }
        const int j = iperm[base + li];
        out[b * (2 * NK) + 2 * j]     = m;
        out[b * (2 * NK) + 2 * j + 1] = (float)c / (float)Lo;
    }
}

__global__ __launch_bounds__(256) void rocket_pad_kernel(
    const float* __restrict__ xp,
    const float* __restrict__ w0, const float* __restrict__ b0,
    const int* __restrict__ off0, const int* __restrict__ l0,
    const float* __restrict__ w1, const float* __restrict__ b1,
    const int* __restrict__ off1, const int* __restrict__ l1,
    const float* __restrict__ w2, const float* __restrict__ b2,
    const int* __restrict__ off2, const int* __restrict__ l2,
    const int* __restrict__ iperm, int n0, int n01,
    float* __restrict__ out)
{
    const int gid = blockIdx.x;
    const int b   = blockIdx.y;
    const float* xr = xp + (size_t)b * ROWS;
    if (gid < n0) {
        rocket_block_pad<7>(xr, w0, b0, off0, l0, iperm, 0, gid, b, out);
    } else if (gid < n01) {
        rocket_block_pad<9>(xr, w1, b1, off1, l1, iperm, n0, gid - n0, b, out);
    } else {
        rocket_block_pad<11>(xr, w2, b2, off2, l2, iperm, n01, gid - n01, b, out);
    }
}

// ---------------- fallback (R2-proven) path ----------------
template <int KS>
__device__ __forceinline__ void rocket_block_fb(
    const float* __restrict__ xr,
    const float* __restrict__ w, const float* __restrict__ bias,
    const int* __restrict__ off, const int* __restrict__ lout,
    const int* __restrict__ iperm, int P, int base, int li, int b,
    float* __restrict__ out)
{
    const int tid = threadIdx.x;
    float wk[KS];
#pragma unroll
    for (int k = 0; k < KS; ++k) wk[k] = w[li * KS + k];
    const int o0  = off[li * KS + 0];
    const int o1  = off[li * KS + 1];
    const int d   = o1 - o0;
    const int pad = P - o0;
    const float bi = bias[li];
    const int   Lo = lout[li];
    int t_lo = min(pad, Lo);
    int t_hi = min(Lo, LSEQ - (KS - 1) * d + pad);
    if (t_hi < t_lo) t_hi = t_lo;

    float mx = -INFINITY; int cnt = 0;
    for (int t = tid; t < t_lo; t += 256) {
        float y = bi; int idx = t - pad;
#pragma unroll
        for (int k = 0; k < KS; ++k) {
            float xv = ((unsigned)idx < (unsigned)LSEQ) ? xr[idx] : 0.0f;
            y = fmaf(wk[k], xv, y); idx += d;
        }
        mx = fmaxf(mx, y); cnt += (y > 0.0f);
    }
    for (int t = t_lo + tid; t < t_hi; t += 256) {
        float y = bi;
#pragma unroll
        for (int k = 0; k < KS; ++k) y = fmaf(wk[k], xr[(t - pad) + k * d], y);
        mx = fmaxf(mx, y); cnt += (y > 0.0f);
    }
    for (int t = t_hi + tid; t < Lo; t += 256) {
        float y = bi; int idx = t - pad;
#pragma unroll
        for (int k = 0; k < KS; ++k) {
            float xv = ((unsigned)idx < (unsigned)LSEQ) ? xr[idx] : 0.0f;
            y = fmaf(wk[k], xv, y); idx += d;
        }
        mx = fmaxf(mx, y); cnt += (y > 0.0f);
    }
#pragma unroll
    for (int o = 32; o > 0; o >>= 1) {
        mx = fmaxf(mx, __shfl_down(mx, o, 64));
        cnt += __shfl_down(cnt, o, 64);
    }
    __shared__ float smx[4];
    __shared__ int   scnt[4];
    const int wid = tid >> 6;
    if ((tid & 63) == 0) { smx[wid] = mx; scnt[wid] = cnt; }
    __syncthreads();
    if (tid == 0) {
        float m = smx[0]; int c = scnt[0];
#pragma unroll
        for (int i = 1; i < 4; ++i) { m = fmaxf(m, smx[i]); c += scnt[i]; }
        const int j = iperm[base + li];
        out[b * (2 * NK) + 2 * j]     = m;
        out[b * (2 * NK) + 2 * j + 1] = (float)c / (float)Lo;
    }
}

__global__ __launch_bounds__(256) void rocket_fb_kernel(
    const float* __restrict__ x,
    const float* __restrict__ w0, const float* __restrict__ b0,
    const int* __restrict__ off0, const int* __restrict__ l0,
    const float* __restrict__ w1, const float* __restrict__ b1,
    const int* __restrict__ off1, const int* __restrict__ l1,
    const float* __restrict__ w2, const float* __restrict__ b2,
    const int* __restrict__ off2, const int* __restrict__ l2,
    const int* __restrict__ iperm, const int* __restrict__ Pp,
    int n0, int n01, float* __restrict__ out)
{
    const int gid = blockIdx.x;
    const int b   = blockIdx.y;
    const int P   = *Pp;
    const float* xr = x + (size_t)b * LSEQ;
    if (gid < n0) {
        rocket_block_fb<7>(xr, w0, b0, off0, l0, iperm, P, 0, gid, b, out);
    } else if (gid < n01) {
        rocket_block_fb<9>(xr, w1, b1, off1, l1, iperm, P, n0, gid - n0, b, out);
    } else {
        rocket_block_fb<11>(xr, w2, b2, off2, l2, iperm, P, n01, gid - n01, b, out);
    }
}

extern "C" void kernel_launch(void* const* d_in, const int* in_sizes, int n_in,
                              void* d_out, int out_size, void* d_ws, size_t ws_size,
                              hipStream_t stream) {
    const float* x    = (const float*)d_in[0];
    const int*   perm = (const int*)d_in[1];
    const int*   Pp   = (const int*)d_in[2];
    const float* w0   = (const float*)d_in[3];
    const float* b0   = (const float*)d_in[4];
    const int*   off0 = (const int*)d_in[5];
    const int*   l0   = (const int*)d_in[6];
    const float* w1   = (const float*)d_in[7];
    const float* b1   = (const float*)d_in[8];
    const int*   off1 = (const int*)d_in[9];
    const int*   l1   = (const int*)d_in[10];
    const float* w2   = (const float*)d_in[11];
    const float* b2   = (const float*)d_in[12];
    const int*   off2 = (const int*)d_in[13];
    const int*   l2   = (const int*)d_in[14];

    const int n0 = in_sizes[4];
    const int n1 = in_sizes[8];

    float* out = (float*)d_out;

    const size_t need = (size_t)NB * ROWS * sizeof(float) + NK * sizeof(int);
    if (ws_size >= need) {
        float* xp   = (float*)d_ws;
        int*  iperm = (int*)((float*)d_ws + (size_t)NB * ROWS);
        build_iperm_kernel<<<1, NK, 0, stream>>>(perm, iperm);
        pad_x_kernel<<<dim3(ROWS / 256, NB), 256, 0, stream>>>(x, xp, Pp);
        rocket_pad_kernel<<<dim3(NK, NB), 256, 0, stream>>>(
            xp, w0, b0, off0, l0, w1, b1, off1, l1, w2, b2, off2, l2,
            iperm, n0, n0 + n1, out);
    } else {
        int* iperm = (int*)d_ws;
        build_iperm_kernel<<<1, NK, 0, stream>>>(perm, iperm);
        rocket_fb_kernel<<<dim3(NK, NB), 256, 0, stream>>>(
            x, w0, b0, off0, l0, w1, b1, off1, l1, w2, b2, off2, l2,
            iperm, Pp, n0, n0 + n1, out);
    }
}

// Round 6
// 48.947 us; speedup vs baseline: 1.6116x; 1.1057x over previous
//
#include <hip/hip_runtime.h>
#include <math.h>

#define LSEQ 4096
#define NK 512
#define NB 16

template <int KS>
__device__ __forceinline__ void rocket_body(
    const float* __restrict__ sx,     // LDS-staged x row [LSEQ]
    const float* __restrict__ w, const float* __restrict__ bias,
    const int* __restrict__ off, const int* __restrict__ lout,
    int P, int li, int b, int outj,
    float* __restrict__ out, float* smx, int* scnt)
{
    const int tid = threadIdx.x;

    float wk[KS];
#pragma unroll
    for (int k = 0; k < KS; ++k) wk[k] = w[li * KS + k];
    const int o0  = off[li * KS + 0];
    const int o1  = off[li * KS + 1];
    const int d   = o1 - o0;          // dilation
    const int pad = P - o0;           // total (doubled) pad
    const float bi = bias[li];
    const int   Lo = lout[li];

    // interior: all taps idx = t - pad + k*d in [0, LSEQ)
    int t_lo = min(pad, Lo);
    int t_hi = min(Lo, LSEQ - (KS - 1) * d + pad);
    if (t_hi < t_lo) t_hi = t_lo;

    float mx  = -INFINITY;
    int   cnt = 0;

    // ---- left edge [0, t_lo): clamp + select-zero, taps from LDS ----
    for (int t = tid; t < t_lo; t += 256) {
        float y = bi;
        int idx = t - pad;
#pragma unroll
        for (int k = 0; k < KS; ++k) {
            int ic = min(max(idx, 0), LSEQ - 1);
            float xv = sx[ic];
            xv = ((unsigned)idx < (unsigned)LSEQ) ? xv : 0.0f;
            y = fmaf(wk[k], xv, y);
            idx += d;
        }
        mx = fmaxf(mx, y); cnt += (y > 0.0f);
    }

    // ---- interior [t_lo, t_hi): unchecked LDS taps, lane-consecutive t ----
    for (int t = t_lo + tid; t < t_hi; t += 256) {
        const float* p = sx + (t - pad);
        float y = bi;
#pragma unroll
        for (int k = 0; k < KS; ++k) y = fmaf(wk[k], p[k * d], y);
        mx = fmaxf(mx, y); cnt += (y > 0.0f);
    }

    // ---- right edge [t_hi, Lo): clamp + select-zero, taps from LDS ----
    for (int t = t_hi + tid; t < Lo; t += 256) {
        float y = bi;
        int idx = t - pad;
#pragma unroll
        for (int k = 0; k < KS; ++k) {
            int ic = min(max(idx, 0), LSEQ - 1);
            float xv = sx[ic];
            xv = ((unsigned)idx < (unsigned)LSEQ) ? xv : 0.0f;
            y = fmaf(wk[k], xv, y);
            idx += d;
        }
        mx = fmaxf(mx, y); cnt += (y > 0.0f);
    }

    // ---- wave64 + block reduction ----
#pragma unroll
    for (int o = 32; o > 0; o >>= 1) {
        mx = fmaxf(mx, __shfl_down(mx, o, 64));
        cnt += __shfl_down(cnt, o, 64);
    }
    const int wid = tid >> 6;
    if ((tid & 63) == 0) { smx[wid] = mx; scnt[wid] = cnt; }
    __syncthreads();
    if (tid == 0) {
        float m = smx[0]; int c = scnt[0];
#pragma unroll
        for (int i = 1; i < 4; ++i) { m = fmaxf(m, smx[i]); c += scnt[i]; }
        out[b * (2 * NK) + 2 * outj]     = m;
        out[b * (2 * NK) + 2 * outj + 1] = (float)c / (float)Lo;
    }
}

__global__ __launch_bounds__(256) void rocket_lds_kernel(
    const float* __restrict__ x, const int* __restrict__ perm,
    const int* __restrict__ Pp,
    const float* __restrict__ w0, const float* __restrict__ b0,
    const int* __restrict__ off0, const int* __restrict__ l0,
    const float* __restrict__ w1, const float* __restrict__ b1,
    const int* __restrict__ off1, const int* __restrict__ l1,
    const float* __restrict__ w2, const float* __restrict__ b2,
    const int* __restrict__ off2, const int* __restrict__ l2,
    int n0, int n01,
    float* __restrict__ out)
{
    __shared__ float sx[LSEQ];
    __shared__ int   sj;
    __shared__ float smx[4];
    __shared__ int   scnt[4];

    const int gid = blockIdx.x;   // global kernel index (group-ordered)
    const int b   = blockIdx.y;
    const int tid = threadIdx.x;

    // inverse permutation lookup: sj = j with perm[j] == gid (exactly one match)
    if (perm[tid]       == gid) sj = tid;
    if (perm[tid + 256] == gid) sj = tid + 256;

    // stage x row into LDS (coalesced float4)
    const float4* x4 = (const float4*)(x + (size_t)b * LSEQ);
    float4* s4 = (float4*)sx;
#pragma unroll
    for (int i = 0; i < LSEQ / 4 / 256; ++i) s4[tid + 256 * i] = x4[tid + 256 * i];
    __syncthreads();

    const int P = *Pp;
    const int outj = sj;

    if (gid < n0) {
        rocket_body<7>(sx, w0, b0, off0, l0, P, gid, b, outj, out, smx, scnt);
    } else if (gid < n01) {
        rocket_body<9>(sx, w1, b1, off1, l1, P, gid - n0, b, outj, out, smx, scnt);
    } else {
        rocket_body<11>(sx, w2, b2, off2, l2, P, gid - n01, b, outj, out, smx, scnt);
    }
}

extern "C" void kernel_launch(void* const* d_in, const int* in_sizes, int n_in,
                              void* d_out, int out_size, void* d_ws, size_t ws_size,
                              hipStream_t stream) {
    const float* x    = (const float*)d_in[0];
    const int*   perm = (const int*)d_in[1];
    const int*   Pp   = (const int*)d_in[2];
    const float* w0   = (const float*)d_in[3];
    const float* b0   = (const float*)d_in[4];
    const int*   off0 = (const int*)d_in[5];
    const int*   l0   = (const int*)d_in[6];
    const float* w1   = (const float*)d_in[7];
    const float* b1   = (const float*)d_in[8];
    const int*   off1 = (const int*)d_in[9];
    const int*   l1   = (const int*)d_in[10];
    const float* w2   = (const float*)d_in[11];
    const float* b2   = (const float*)d_in[12];
    const int*   off2 = (const int*)d_in[13];
    const int*   l2   = (const int*)d_in[14];

    const int n0 = in_sizes[4];
    const int n1 = in_sizes[8];

    float* out = (float*)d_out;

    rocket_lds_kernel<<<dim3(NK, NB), 256, 0, stream>>>(
        x, perm, Pp, w0, b0, off0, l0, w1, b1, off1, l1, w2, b2, off2, l2,
        n0, n0 + n1, out);
}